// Round 1
// baseline (462.659 us; speedup 1.0000x reference)
//
#include <hip/hip_runtime.h>
#include <hip/hip_bf16.h>

#define B_ 8
#define N_ 512
#define E_ 8192
#define G_ 1024
#define V_ 100000
#define HD_ 1024
#define FIN_ 20
#define EPS_ 1e-5f

// ---------- transpose fc_init_w [HD][FIN] -> wT [FIN][HD] ----------
__global__ void k_transpose_w(const float* __restrict__ w, float* __restrict__ wT) {
    int idx = blockIdx.x * blockDim.x + threadIdx.x;
    if (idx >= FIN_ * HD_) return;
    int k = idx / HD_, d = idx % HD_;
    wT[idx] = w[d * FIN_ + k];
}

// ---------- x0[b][n][d] = h[b][n][:] @ wT[:,d] + bias[d] ----------
__global__ void k_fc_init(const float* __restrict__ h, const float* __restrict__ wT,
                          const float* __restrict__ bias, float* __restrict__ x0) {
    int bn = blockIdx.x; // b*N + n
    __shared__ float hs[FIN_];
    if (threadIdx.x < FIN_) hs[threadIdx.x] = h[bn * FIN_ + threadIdx.x];
    __syncthreads();
    for (int d = threadIdx.x; d < HD_; d += blockDim.x) {
        float acc = bias[d];
#pragma unroll
        for (int k = 0; k < FIN_; ++k) acc += hs[k] * wT[k * HD_ + d];
        x0[(size_t)bn * HD_ + d] = acc;
    }
}

// ---------- CSR build ----------
__global__ void k_deg(const int* __restrict__ dst, int* __restrict__ deg) {
    int idx = blockIdx.x * blockDim.x + threadIdx.x;
    if (idx >= B_ * E_) return;
    int b = idx / E_;
    atomicAdd(&deg[b * N_ + dst[idx]], 1);
}

__global__ void k_scan(const int* __restrict__ deg, int* __restrict__ offs,
                       int* __restrict__ cursor) {
    __shared__ int s[N_];
    int b = blockIdx.x, t = threadIdx.x;
    int d = deg[b * N_ + t];
    s[t] = d;
    __syncthreads();
    for (int off = 1; off < N_; off <<= 1) {
        int v = (t >= off) ? s[t - off] : 0;
        __syncthreads();
        s[t] += v;
        __syncthreads();
    }
    int excl = s[t] - d;
    offs[b * N_ + t] = excl;
    cursor[b * N_ + t] = excl;
}

__global__ void k_scatter(const int* __restrict__ src, const int* __restrict__ dst,
                          int* __restrict__ cursor, int* __restrict__ csr) {
    int idx = blockIdx.x * blockDim.x + threadIdx.x;
    if (idx >= B_ * E_) return;
    int b = idx / E_;
    int d = dst[idx];
    int pos = atomicAdd(&cursor[b * N_ + d], 1);
    csr[b * E_ + pos] = src[idx];
}

// ---------- GIN aggregate + BN partial stats ----------
// grid (HD/128, N/64, B), block 256 (128 cols x 2 row-groups)
__global__ void k_agg(const float* __restrict__ xin, float* __restrict__ y,
                      const int* __restrict__ deg, const int* __restrict__ offs,
                      const int* __restrict__ csr,
                      float* __restrict__ csum, float* __restrict__ csumsq) {
    int b = blockIdx.z;
    int rowbase = blockIdx.y * 64;
    int colbase = blockIdx.x * 128;
    int tx = threadIdx.x & 127;
    int ty = threadIdx.x >> 7;
    int col = colbase + tx;
    const float* xb = xin + (size_t)b * N_ * HD_;
    float psum = 0.f, psq = 0.f;
    for (int r = ty; r < 64; r += 2) {
        int node = rowbase + r;
        int dg = deg[b * N_ + node];
        float v = xb[(size_t)node * HD_ + col];
        if (dg > 0) {
            int st = offs[b * N_ + node];
            float nsum = 0.f;
            for (int i = 0; i < dg; ++i) {
                int s = csr[b * E_ + st + i];
                nsum += xb[(size_t)s * HD_ + col];
            }
            v += nsum / (float)dg;
        }
        y[((size_t)b * N_ + node) * HD_ + col] = v;
        psum += v;
        psq += v * v;
    }
    __shared__ float red[2][128];
    red[ty][tx] = psum;
    __syncthreads();
    if (ty == 0) atomicAdd(&csum[b * HD_ + col], red[0][tx] + red[1][tx]);
    __syncthreads();
    red[ty][tx] = psq;
    __syncthreads();
    if (ty == 0) atomicAdd(&csumsq[b * HD_ + col], red[0][tx] + red[1][tx]);
}

// ---------- BN normalize + relu ----------
__global__ void k_norm(const float* __restrict__ y, float* __restrict__ xout,
                       const float* __restrict__ csum, const float* __restrict__ csumsq,
                       const float* __restrict__ gg, const float* __restrict__ bb) {
    int idx = blockIdx.x * blockDim.x + threadIdx.x;
    const int total = B_ * N_ * HD_;
    if (idx >= total) return;
    int d = idx & (HD_ - 1);
    int b = idx / (N_ * HD_);
    float mu = csum[b * HD_ + d] * (1.f / N_);
    float var = csumsq[b * HD_ + d] * (1.f / N_) - mu * mu;
    float rs = rsqrtf(var + EPS_);
    float v = (y[idx] - mu) * rs * gg[d] + bb[d];
    xout[idx] = v > 0.f ? v : 0.f;
}

// ---------- graph mean pool ----------
// grid (HD/64, B), block 256 (64 d x 4 row-groups)
__global__ void k_qemb(const float* __restrict__ x, float* __restrict__ qemb) {
    int b = blockIdx.y;
    int tx = threadIdx.x & 63;
    int ty = threadIdx.x >> 6;
    int d = blockIdx.x * 64 + tx;
    const float* xb = x + (size_t)b * N_ * HD_;
    float s = 0.f;
    for (int n = ty; n < N_; n += 4) s += xb[(size_t)n * HD_ + d];
    __shared__ float red[4][64];
    red[ty][tx] = s;
    __syncthreads();
    if (ty == 0)
        qemb[b * HD_ + d] = (red[0][tx] + red[1][tx] + red[2][tx] + red[3][tx]) * (1.f / N_);
}

// ---------- r0[b][j] = fc_b[j] + fc_w[j][0:1024] . qemb[b] ----------
__global__ void k_r0(const float* __restrict__ fc_w, const float* __restrict__ fc_b,
                     const float* __restrict__ qemb, float* __restrict__ r0) {
    int b = blockIdx.x >> 7;
    int j = blockIdx.x & 127;
    int lane = threadIdx.x;
    const float* wr = fc_w + (size_t)j * (2 * HD_);
    const float* q = qemb + b * HD_;
    float acc = 0.f;
    for (int d = lane; d < HD_; d += 64) acc += wr[d] * q[d];
    for (int off = 32; off; off >>= 1) acc += __shfl_down(acc, off, 64);
    if (lane == 0) r0[b * 128 + j] = acc + fc_b[j];
}

// ---------- main GEMM: z[b][g][j] = r0[b][j] + emb[gPos[b][g]] . fc_w[j][1024:2048] ----------
// grid (G/32, B), block 256. Tile 32g x 128j, BK=32.
#define BK_ 32
__global__ __launch_bounds__(256) void k_gemm(
    const int* __restrict__ gPos, const float* __restrict__ emb,
    const float* __restrict__ fc_w, const float* __restrict__ r0,
    float* __restrict__ z, float* __restrict__ zsum, float* __restrict__ zsumsq) {
    int b = blockIdx.y;
    int gbase = blockIdx.x * 32;
    int tid = threadIdx.x;
    int tj = tid & 15;  // j group of 8
    int tg = tid >> 4;  // g group of 2
    __shared__ int gidx[32];
    __shared__ float As[BK_][36];
    __shared__ float Bs[BK_][132];
    if (tid < 32) gidx[tid] = gPos[b * G_ + gbase + tid];
    __syncthreads();
    float acc[2][8];
#pragma unroll
    for (int i = 0; i < 2; ++i)
#pragma unroll
        for (int jj = 0; jj < 8; ++jj) acc[i][jj] = 0.f;

    for (int dbase = 0; dbase < HD_; dbase += BK_) {
        {   // A: 32 rows x 32 cols
            int g = tid >> 3, kq = tid & 7;
            const float4 av = *(const float4*)&emb[(size_t)gidx[g] * HD_ + dbase + kq * 4];
            As[kq * 4 + 0][g] = av.x;
            As[kq * 4 + 1][g] = av.y;
            As[kq * 4 + 2][g] = av.z;
            As[kq * 4 + 3][g] = av.w;
        }
        {   // B: 128 rows x 32 cols (second half of fc_w)
            int j = tid >> 1;
            int k0 = (tid & 1) * 16;
            const float* wrow = &fc_w[(size_t)j * (2 * HD_) + HD_ + dbase + k0];
#pragma unroll
            for (int i = 0; i < 4; ++i) {
                float4 bv = *(const float4*)&wrow[i * 4];
                Bs[k0 + i * 4 + 0][j] = bv.x;
                Bs[k0 + i * 4 + 1][j] = bv.y;
                Bs[k0 + i * 4 + 2][j] = bv.z;
                Bs[k0 + i * 4 + 3][j] = bv.w;
            }
        }
        __syncthreads();
#pragma unroll
        for (int k = 0; k < BK_; ++k) {
            const float2 a = *(const float2*)&As[k][tg * 2];
            const float4 b0 = *(const float4*)&Bs[k][tj * 8];
            const float4 b1 = *(const float4*)&Bs[k][tj * 8 + 4];
            acc[0][0] += a.x * b0.x; acc[0][1] += a.x * b0.y;
            acc[0][2] += a.x * b0.z; acc[0][3] += a.x * b0.w;
            acc[0][4] += a.x * b1.x; acc[0][5] += a.x * b1.y;
            acc[0][6] += a.x * b1.z; acc[0][7] += a.x * b1.w;
            acc[1][0] += a.y * b0.x; acc[1][1] += a.y * b0.y;
            acc[1][2] += a.y * b0.z; acc[1][3] += a.y * b0.w;
            acc[1][4] += a.y * b1.x; acc[1][5] += a.y * b1.y;
            acc[1][6] += a.y * b1.z; acc[1][7] += a.y * b1.w;
        }
        __syncthreads();
    }

    const float* r0b = r0 + b * 128;
    float psum[8], psq[8];
#pragma unroll
    for (int jj = 0; jj < 8; ++jj) { psum[jj] = 0.f; psq[jj] = 0.f; }
#pragma unroll
    for (int i = 0; i < 2; ++i) {
        int g = gbase + tg * 2 + i;
        float vv[8];
#pragma unroll
        for (int jj = 0; jj < 8; ++jj) {
            float v = acc[i][jj] + r0b[tj * 8 + jj];
            vv[jj] = v;
            psum[jj] += v;
            psq[jj] += v * v;
        }
        float* zr = &z[((size_t)b * G_ + g) * 128 + tj * 8];
        *(float4*)&zr[0] = make_float4(vv[0], vv[1], vv[2], vv[3]);
        *(float4*)&zr[4] = make_float4(vv[4], vv[5], vv[6], vv[7]);
    }
    __shared__ float red[16][128];
#pragma unroll
    for (int jj = 0; jj < 8; ++jj) red[tg][tj * 8 + jj] = psum[jj];
    __syncthreads();
    if (tid < 128) {
        float s = 0.f;
#pragma unroll
        for (int t = 0; t < 16; ++t) s += red[t][tid];
        atomicAdd(&zsum[b * 128 + tid], s);
    }
    __syncthreads();
#pragma unroll
    for (int jj = 0; jj < 8; ++jj) red[tg][tj * 8 + jj] = psq[jj];
    __syncthreads();
    if (tid < 128) {
        float s = 0.f;
#pragma unroll
        for (int t = 0; t < 16; ++t) s += red[t][tid];
        atomicAdd(&zsumsq[b * 128 + tid], s);
    }
}

// ---------- BN3 + relu + fc2 + sigmoid ----------
// one wave per (b,g)
__global__ void k_final(const float* __restrict__ z, const float* __restrict__ zsum,
                        const float* __restrict__ zsumsq, const float* __restrict__ g3,
                        const float* __restrict__ b3, const float* __restrict__ fc2w,
                        const float* __restrict__ fc2b, float* __restrict__ out) {
    int wid = (blockIdx.x * blockDim.x + threadIdx.x) >> 6;
    int lane = threadIdx.x & 63;
    if (wid >= B_ * G_) return;
    int b = wid / G_;
    const float* zr = z + (size_t)wid * 128;
    float acc = 0.f;
#pragma unroll
    for (int t = 0; t < 2; ++t) {
        int j = lane + t * 64;
        float mu = zsum[b * 128 + j] * (1.f / G_);
        float var = zsumsq[b * 128 + j] * (1.f / G_) - mu * mu;
        float v = (zr[j] - mu) * rsqrtf(var + EPS_) * g3[j] + b3[j];
        v = v > 0.f ? v : 0.f;
        acc += v * fc2w[j];
    }
    for (int off = 32; off; off >>= 1) acc += __shfl_down(acc, off, 64);
    if (lane == 0) out[wid] = 1.f / (1.f + expf(-(acc + fc2b[0])));
}

extern "C" void kernel_launch(void* const* d_in, const int* in_sizes, int n_in,
                              void* d_out, int out_size, void* d_ws, size_t ws_size,
                              hipStream_t stream) {
    const float* h      = (const float*)d_in[0];
    const int*   src    = (const int*)d_in[1];
    const int*   dst    = (const int*)d_in[2];
    const int*   gPos   = (const int*)d_in[3];
    const float* emb    = (const float*)d_in[4];
    const float* fciw   = (const float*)d_in[5];
    const float* fcib   = (const float*)d_in[6];
    const float* bn1g   = (const float*)d_in[7];
    const float* bn1b   = (const float*)d_in[8];
    const float* bn2g   = (const float*)d_in[9];
    const float* bn2b   = (const float*)d_in[10];
    const float* fc_w   = (const float*)d_in[11];
    const float* fc_b   = (const float*)d_in[12];
    const float* bn3g   = (const float*)d_in[13];
    const float* bn3b   = (const float*)d_in[14];
    const float* fc2w   = (const float*)d_in[15];
    const float* fc2b   = (const float*)d_in[16];
    float* out = (float*)d_out;

    char* w = (char*)d_ws;
    float* bufA = (float*)w; w += (size_t)B_ * N_ * HD_ * 4;
    float* bufY = (float*)w; w += (size_t)B_ * N_ * HD_ * 4;
    float* z    = (float*)w; w += (size_t)B_ * G_ * 128 * 4;
    float* wT   = (float*)w; w += (size_t)FIN_ * HD_ * 4;
    float* qemb = (float*)w; w += (size_t)B_ * HD_ * 4;
    float* r0   = (float*)w; w += (size_t)B_ * 128 * 4;
    int* offs   = (int*)w;   w += (size_t)B_ * N_ * 4;
    int* csr    = (int*)w;   w += (size_t)B_ * E_ * 4;
    // zeroed accumulator region
    char* zbase = w;
    int* deg    = (int*)w;   w += (size_t)B_ * N_ * 4;
    int* cursor = (int*)w;   w += (size_t)B_ * N_ * 4;
    float* cs1  = (float*)w; w += (size_t)B_ * HD_ * 4;
    float* cq1  = (float*)w; w += (size_t)B_ * HD_ * 4;
    float* cs2  = (float*)w; w += (size_t)B_ * HD_ * 4;
    float* cq2  = (float*)w; w += (size_t)B_ * HD_ * 4;
    float* zsum = (float*)w; w += (size_t)B_ * 128 * 4;
    float* zsq  = (float*)w; w += (size_t)B_ * 128 * 4;
    size_t zero_bytes = (size_t)(w - zbase);

    hipMemsetAsync(zbase, 0, zero_bytes, stream);

    k_transpose_w<<<(FIN_ * HD_ + 255) / 256, 256, 0, stream>>>(fciw, wT);
    k_fc_init<<<B_ * N_, 256, 0, stream>>>(h, wT, fcib, bufA);

    k_deg<<<(B_ * E_) / 256, 256, 0, stream>>>(dst, deg);
    k_scan<<<B_, N_, 0, stream>>>(deg, offs, cursor);
    k_scatter<<<(B_ * E_) / 256, 256, 0, stream>>>(src, dst, cursor, csr);

    dim3 agrid(HD_ / 128, N_ / 64, B_);
    k_agg<<<agrid, 256, 0, stream>>>(bufA, bufY, deg, offs, csr, cs1, cq1);
    k_norm<<<(B_ * N_ * HD_) / 256, 256, 0, stream>>>(bufY, bufA, cs1, cq1, bn1g, bn1b);
    k_agg<<<agrid, 256, 0, stream>>>(bufA, bufY, deg, offs, csr, cs2, cq2);
    k_norm<<<(B_ * N_ * HD_) / 256, 256, 0, stream>>>(bufY, bufA, cs2, cq2, bn2g, bn2b);

    k_qemb<<<dim3(HD_ / 64, B_), 256, 0, stream>>>(bufA, qemb);
    k_r0<<<B_ * 128, 64, 0, stream>>>(fc_w, fc_b, qemb, r0);

    k_gemm<<<dim3(G_ / 32, B_), 256, 0, stream>>>(gPos, emb, fc_w, r0, z, zsum, zsq);
    k_final<<<(B_ * G_) / 4, 256, 0, stream>>>(z, zsum, zsq, bn3g, bn3b, fc2w, fc2b, out);
}

// Round 2
// 323.928 us; speedup vs baseline: 1.4283x; 1.4283x over previous
//
#include <hip/hip_runtime.h>
#include <hip/hip_bf16.h>

#define B_ 8
#define N_ 512
#define E_ 8192
#define G_ 1024
#define V_ 100000
#define HD_ 1024
#define FIN_ 20
#define EPS_ 1e-5f

typedef __attribute__((ext_vector_type(8))) short bf16x8;
typedef __attribute__((ext_vector_type(4))) float f32x4;

__device__ inline short f2bf(float f) {
    unsigned u = __builtin_bit_cast(unsigned, f);
    unsigned r = (u + 0x7fffu + ((u >> 16) & 1u)) >> 16;
    return (short)r;
}

// ---------- x0[bn][d] = h[bn][:] @ fc_init_w[d][:] + bias[d] ----------
// grid B*N/16, block 256; each block does 16 nodes x 1024 d
__global__ __launch_bounds__(256) void k_fc_init(const float* __restrict__ h,
                                                 const float* __restrict__ w,
                                                 const float* __restrict__ bias,
                                                 float* __restrict__ x0) {
    int nb = blockIdx.x * 16;
    int tid = threadIdx.x;
    __shared__ float hs[16 * FIN_];
    if (tid < 16 * FIN_) hs[tid] = h[nb * FIN_ + tid];
    __syncthreads();
#pragma unroll
    for (int dq = 0; dq < 4; ++dq) {
        int d = dq * 256 + tid;
        const float4* wr = (const float4*)&w[d * FIN_];
        float4 w4[5];
#pragma unroll
        for (int i = 0; i < 5; ++i) w4[i] = wr[i];
        float bsv = bias[d];
#pragma unroll 4
        for (int n = 0; n < 16; ++n) {
            const float* hn = &hs[n * FIN_];
            float acc = bsv;
#pragma unroll
            for (int i = 0; i < 5; ++i) {
                acc += w4[i].x * hn[i * 4 + 0] + w4[i].y * hn[i * 4 + 1] +
                       w4[i].z * hn[i * 4 + 2] + w4[i].w * hn[i * 4 + 3];
            }
            x0[(size_t)(nb + n) * HD_ + d] = acc;
        }
    }
}

// ---------- fused CSR build: deg + scan + scatter, one block per graph ----------
__global__ __launch_bounds__(512) void k_graph(const int* __restrict__ src,
                                               const int* __restrict__ dst,
                                               int* __restrict__ deg, int* __restrict__ offs,
                                               int* __restrict__ csr) {
    int b = blockIdx.x, t = threadIdx.x;
    __shared__ int sdeg[N_], s[N_], scur[N_];
    sdeg[t] = 0;
    __syncthreads();
    for (int e = t; e < E_; e += 512) atomicAdd(&sdeg[dst[b * E_ + e]], 1);
    __syncthreads();
    int d = sdeg[t];
    s[t] = d;
    __syncthreads();
    for (int off = 1; off < N_; off <<= 1) {
        int v = (t >= off) ? s[t - off] : 0;
        __syncthreads();
        s[t] += v;
        __syncthreads();
    }
    int excl = s[t] - d;
    deg[b * N_ + t] = d;
    offs[b * N_ + t] = excl;
    scur[t] = excl;
    __syncthreads();
    for (int e = t; e < E_; e += 512) {
        int dd = dst[b * E_ + e];
        int pos = atomicAdd(&scur[dd], 1);
        csr[b * E_ + pos] = src[b * E_ + e];
    }
}

// ---------- GIN aggregate (float4) + BN partial stats ----------
// grid (HD/256, N/64, B), block 256 (64 float4-cols x 4 row-groups)
__global__ __launch_bounds__(256) void k_agg(const float4* __restrict__ xin,
                                             float4* __restrict__ y,
                                             const int* __restrict__ deg,
                                             const int* __restrict__ offs,
                                             const int* __restrict__ csr,
                                             float* __restrict__ csum,
                                             float* __restrict__ csumsq) {
    int b = blockIdx.z;
    int rowbase = blockIdx.y * 64;
    int tx = threadIdx.x & 63, ty = threadIdx.x >> 6;
    int c4 = blockIdx.x * 64 + tx;
    const float4* xb = xin + (size_t)b * N_ * (HD_ / 4);
    float4 ps = {0.f, 0.f, 0.f, 0.f}, pq = {0.f, 0.f, 0.f, 0.f};
    for (int r = ty; r < 64; r += 4) {
        int node = rowbase + r;
        int dg = deg[b * N_ + node];
        float4 v = xb[(size_t)node * (HD_ / 4) + c4];
        if (dg > 0) {
            int st = offs[b * N_ + node];
            float4 ns = {0.f, 0.f, 0.f, 0.f};
            for (int i = 0; i < dg; ++i) {
                int sI = csr[b * E_ + st + i];
                float4 xs = xb[(size_t)sI * (HD_ / 4) + c4];
                ns.x += xs.x; ns.y += xs.y; ns.z += xs.z; ns.w += xs.w;
            }
            float inv = 1.f / (float)dg;
            v.x += ns.x * inv; v.y += ns.y * inv; v.z += ns.z * inv; v.w += ns.w * inv;
        }
        y[((size_t)b * N_ + node) * (HD_ / 4) + c4] = v;
        ps.x += v.x; ps.y += v.y; ps.z += v.z; ps.w += v.w;
        pq.x += v.x * v.x; pq.y += v.y * v.y; pq.z += v.z * v.z; pq.w += v.w * v.w;
    }
    __shared__ float4 red[256];
    red[threadIdx.x] = ps;
    __syncthreads();
    if (ty == 0) {
        float4 a = red[tx], b1 = red[64 + tx], c = red[128 + tx], d1 = red[192 + tx];
        atomicAdd(&csum[b * HD_ + c4 * 4 + 0], a.x + b1.x + c.x + d1.x);
        atomicAdd(&csum[b * HD_ + c4 * 4 + 1], a.y + b1.y + c.y + d1.y);
        atomicAdd(&csum[b * HD_ + c4 * 4 + 2], a.z + b1.z + c.z + d1.z);
        atomicAdd(&csum[b * HD_ + c4 * 4 + 3], a.w + b1.w + c.w + d1.w);
    }
    __syncthreads();
    red[threadIdx.x] = pq;
    __syncthreads();
    if (ty == 0) {
        float4 a = red[tx], b1 = red[64 + tx], c = red[128 + tx], d1 = red[192 + tx];
        atomicAdd(&csumsq[b * HD_ + c4 * 4 + 0], a.x + b1.x + c.x + d1.x);
        atomicAdd(&csumsq[b * HD_ + c4 * 4 + 1], a.y + b1.y + c.y + d1.y);
        atomicAdd(&csumsq[b * HD_ + c4 * 4 + 2], a.z + b1.z + c.z + d1.z);
        atomicAdd(&csumsq[b * HD_ + c4 * 4 + 3], a.w + b1.w + c.w + d1.w);
    }
}

// ---------- BN normalize + relu (float4) ----------
__global__ __launch_bounds__(256) void k_norm(const float4* __restrict__ y,
                                              float4* __restrict__ xout,
                                              const float4* __restrict__ csum,
                                              const float4* __restrict__ csumsq,
                                              const float4* __restrict__ gg,
                                              const float4* __restrict__ bb) {
    int idx = blockIdx.x * blockDim.x + threadIdx.x;  // float4 index
    int d4 = idx & (HD_ / 4 - 1);
    int b = idx >> 17;  // / (N_*HD_/4)
    float4 cs = csum[b * (HD_ / 4) + d4];
    float4 cq = csumsq[b * (HD_ / 4) + d4];
    float4 g4 = gg[d4], b4 = bb[d4];
    float4 v = y[idx];
    float4 o;
    {
        float mu = cs.x * (1.f / N_); float var = cq.x * (1.f / N_) - mu * mu;
        float t = (v.x - mu) * rsqrtf(var + EPS_) * g4.x + b4.x; o.x = t > 0.f ? t : 0.f;
    }
    {
        float mu = cs.y * (1.f / N_); float var = cq.y * (1.f / N_) - mu * mu;
        float t = (v.y - mu) * rsqrtf(var + EPS_) * g4.y + b4.y; o.y = t > 0.f ? t : 0.f;
    }
    {
        float mu = cs.z * (1.f / N_); float var = cq.z * (1.f / N_) - mu * mu;
        float t = (v.z - mu) * rsqrtf(var + EPS_) * g4.z + b4.z; o.z = t > 0.f ? t : 0.f;
    }
    {
        float mu = cs.w * (1.f / N_); float var = cq.w * (1.f / N_) - mu * mu;
        float t = (v.w - mu) * rsqrtf(var + EPS_) * g4.w + b4.w; o.w = t > 0.f ? t : 0.f;
    }
    xout[idx] = o;
}

// ---------- graph mean pool (float4) ----------
// grid (HD/4/64, B), block 256
__global__ void k_qemb(const float4* __restrict__ x, float4* __restrict__ qemb) {
    int b = blockIdx.y;
    int tx = threadIdx.x & 63, ty = threadIdx.x >> 6;
    int d4 = blockIdx.x * 64 + tx;
    const float4* xb = x + (size_t)b * N_ * (HD_ / 4);
    float4 s = {0.f, 0.f, 0.f, 0.f};
    for (int n = ty; n < N_; n += 4) {
        float4 v = xb[(size_t)n * (HD_ / 4) + d4];
        s.x += v.x; s.y += v.y; s.z += v.z; s.w += v.w;
    }
    __shared__ float4 red[256];
    red[threadIdx.x] = s;
    __syncthreads();
    if (ty == 0) {
        float4 a = red[tx], b1 = red[64 + tx], c = red[128 + tx], d1 = red[192 + tx];
        float4 o;
        o.x = (a.x + b1.x + c.x + d1.x) * (1.f / N_);
        o.y = (a.y + b1.y + c.y + d1.y) * (1.f / N_);
        o.z = (a.z + b1.z + c.z + d1.z) * (1.f / N_);
        o.w = (a.w + b1.w + c.w + d1.w) * (1.f / N_);
        qemb[b * (HD_ / 4) + d4] = o;
    }
}

// ---------- r0[b][j] = fc_b[j] + fc_w[j][0:1024] . qemb[b] ----------
__global__ void k_r0(const float* __restrict__ fc_w, const float* __restrict__ fc_b,
                     const float* __restrict__ qemb, float* __restrict__ r0) {
    int b = blockIdx.x >> 7;
    int j = blockIdx.x & 127;
    int lane = threadIdx.x;
    const float* wr = fc_w + (size_t)j * (2 * HD_);
    const float* q = qemb + b * HD_;
    float acc = 0.f;
    for (int d = lane; d < HD_; d += 64) acc += wr[d] * q[d];
    for (int off = 32; off; off >>= 1) acc += __shfl_down(acc, off, 64);
    if (lane == 0) r0[b * 128 + j] = acc + fc_b[j];
}

// ---------- gather emb rows -> bf16 ----------
// grid B*G*128/256 blocks, 256 thr; each thread converts 8 elems
__global__ __launch_bounds__(256) void k_gather(const int* __restrict__ gPos,
                                                const float* __restrict__ emb,
                                                short* __restrict__ embB) {
    int gid = blockIdx.x * blockDim.x + threadIdx.x;
    int row = gid >> 7;           // 0 .. B*G-1
    int t = gid & 127;            // 8-elem chunk
    int v = gPos[row];
    const float4* srcp = (const float4*)&emb[(size_t)v * HD_ + t * 8];
    float4 a = srcp[0], b = srcp[1];
    bf16x8 o;
    o[0] = f2bf(a.x); o[1] = f2bf(a.y); o[2] = f2bf(a.z); o[3] = f2bf(a.w);
    o[4] = f2bf(b.x); o[5] = f2bf(b.y); o[6] = f2bf(b.z); o[7] = f2bf(b.w);
    *(bf16x8*)&embB[(size_t)row * HD_ + t * 8] = o;
}

// ---------- fc_w[:,1024:2048] -> bf16 [128][1024] ----------
__global__ void k_w2cvt(const float* __restrict__ fc_w, short* __restrict__ w2) {
    int gid = blockIdx.x * blockDim.x + threadIdx.x;  // 0 .. 128*1024/8
    int j = gid >> 7;
    int t = gid & 127;
    const float4* srcp = (const float4*)&fc_w[(size_t)j * (2 * HD_) + HD_ + t * 8];
    float4 a = srcp[0], b = srcp[1];
    bf16x8 o;
    o[0] = f2bf(a.x); o[1] = f2bf(a.y); o[2] = f2bf(a.z); o[3] = f2bf(a.w);
    o[4] = f2bf(b.x); o[5] = f2bf(b.y); o[6] = f2bf(b.z); o[7] = f2bf(b.w);
    *(bf16x8*)&w2[(size_t)j * HD_ + t * 8] = o;
}

// ---------- MFMA GEMM: z[b][g][j] = r0[b][j] + embB[b][g] . w2[j] ----------
// grid (G/32, B), 512 thr = 8 waves; block tile 32g x 128j; wave: 16g x 32j
#define APAD_ 40
__global__ __launch_bounds__(512) void k_gemm(const short* __restrict__ embB,
                                              const short* __restrict__ w2,
                                              const float* __restrict__ r0,
                                              float* __restrict__ z,
                                              float* __restrict__ zsum,
                                              float* __restrict__ zsq) {
    int b = blockIdx.y;
    int gbase = blockIdx.x * 32;
    int tid = threadIdx.x;
    int wave = tid >> 6, lane = tid & 63;
    int gq = wave >> 2;   // 0..1 -> 16 g each
    int jq = wave & 3;    // 0..3 -> 32 j each
    __shared__ short As[32 * APAD_];
    __shared__ short Bs[128 * APAD_];
    f32x4 acc0 = {0.f, 0.f, 0.f, 0.f}, acc1 = {0.f, 0.f, 0.f, 0.f};
    const size_t abase = (size_t)(b * G_ + gbase) * HD_;

    int srow = tid >> 2, skq = (tid & 3) * 8;
    for (int kt = 0; kt < 32; ++kt) {
        int kb = kt * 32;
        if (tid < 128) {
            bf16x8 av = *(const bf16x8*)&embB[abase + (size_t)srow * HD_ + kb + skq];
            *(bf16x8*)&As[srow * APAD_ + skq] = av;
        }
        {
            bf16x8 bv = *(const bf16x8*)&w2[(size_t)srow * HD_ + kb + skq];
            *(bf16x8*)&Bs[srow * APAD_ + skq] = bv;
        }
        __syncthreads();
        bf16x8 a  = *(const bf16x8*)&As[(gq * 16 + (lane & 15)) * APAD_ + (lane >> 4) * 8];
        bf16x8 b0 = *(const bf16x8*)&Bs[(jq * 32 + (lane & 15)) * APAD_ + (lane >> 4) * 8];
        bf16x8 b1 = *(const bf16x8*)&Bs[(jq * 32 + 16 + (lane & 15)) * APAD_ + (lane >> 4) * 8];
        acc0 = __builtin_amdgcn_mfma_f32_16x16x32_bf16(a, b0, acc0, 0, 0, 0);
        acc1 = __builtin_amdgcn_mfma_f32_16x16x32_bf16(a, b1, acc1, 0, 0, 0);
        __syncthreads();
    }

    int col0 = jq * 32 + (lane & 15);
    int col1 = col0 + 16;
    int rbase = gq * 16 + (lane >> 4) * 4;
    const float* r0b = r0 + b * 128;
    float r0c0 = r0b[col0], r0c1 = r0b[col1];
    float s0 = 0.f, q0 = 0.f, s1 = 0.f, q1 = 0.f;
#pragma unroll
    for (int v = 0; v < 4; ++v) {
        int g = gbase + rbase + v;
        float z0 = acc0[v] + r0c0;
        float z1 = acc1[v] + r0c1;
        z[(size_t)(b * G_ + g) * 128 + col0] = z0;
        z[(size_t)(b * G_ + g) * 128 + col1] = z1;
        s0 += z0; q0 += z0 * z0; s1 += z1; q1 += z1 * z1;
    }
    s0 += __shfl_xor(s0, 16, 64); s0 += __shfl_xor(s0, 32, 64);
    q0 += __shfl_xor(q0, 16, 64); q0 += __shfl_xor(q0, 32, 64);
    s1 += __shfl_xor(s1, 16, 64); s1 += __shfl_xor(s1, 32, 64);
    q1 += __shfl_xor(q1, 16, 64); q1 += __shfl_xor(q1, 32, 64);
    if (lane < 16) {
        atomicAdd(&zsum[b * 128 + col0], s0);
        atomicAdd(&zsq[b * 128 + col0], q0);
        atomicAdd(&zsum[b * 128 + col1], s1);
        atomicAdd(&zsq[b * 128 + col1], q1);
    }
}

// ---------- BN3 + relu + fc2 + sigmoid ----------
__global__ void k_final(const float* __restrict__ z, const float* __restrict__ zsum,
                        const float* __restrict__ zsumsq, const float* __restrict__ g3,
                        const float* __restrict__ b3, const float* __restrict__ fc2w,
                        const float* __restrict__ fc2b, float* __restrict__ out) {
    int wid = (blockIdx.x * blockDim.x + threadIdx.x) >> 6;
    int lane = threadIdx.x & 63;
    if (wid >= B_ * G_) return;
    int b = wid / G_;
    const float* zr = z + (size_t)wid * 128;
    float acc = 0.f;
#pragma unroll
    for (int t = 0; t < 2; ++t) {
        int j = lane + t * 64;
        float mu = zsum[b * 128 + j] * (1.f / G_);
        float var = zsumsq[b * 128 + j] * (1.f / G_) - mu * mu;
        float v = (zr[j] - mu) * rsqrtf(var + EPS_) * g3[j] + b3[j];
        v = v > 0.f ? v : 0.f;
        acc += v * fc2w[j];
    }
    for (int off = 32; off; off >>= 1) acc += __shfl_down(acc, off, 64);
    if (lane == 0) out[wid] = 1.f / (1.f + expf(-(acc + fc2b[0])));
}

extern "C" void kernel_launch(void* const* d_in, const int* in_sizes, int n_in,
                              void* d_out, int out_size, void* d_ws, size_t ws_size,
                              hipStream_t stream) {
    const float* h    = (const float*)d_in[0];
    const int*   src  = (const int*)d_in[1];
    const int*   dst  = (const int*)d_in[2];
    const int*   gPos = (const int*)d_in[3];
    const float* emb  = (const float*)d_in[4];
    const float* fciw = (const float*)d_in[5];
    const float* fcib = (const float*)d_in[6];
    const float* bn1g = (const float*)d_in[7];
    const float* bn1b = (const float*)d_in[8];
    const float* bn2g = (const float*)d_in[9];
    const float* bn2b = (const float*)d_in[10];
    const float* fc_w = (const float*)d_in[11];
    const float* fc_b = (const float*)d_in[12];
    const float* bn3g = (const float*)d_in[13];
    const float* bn3b = (const float*)d_in[14];
    const float* fc2w = (const float*)d_in[15];
    const float* fc2b = (const float*)d_in[16];
    float* out = (float*)d_out;

    char* w = (char*)d_ws;
    float* bufA = (float*)w; w += (size_t)B_ * N_ * HD_ * 4;
    float* bufY = (float*)w; w += (size_t)B_ * N_ * HD_ * 4;
    float* z    = (float*)w; w += (size_t)B_ * G_ * 128 * 4;
    short* embB = (short*)w; w += (size_t)B_ * G_ * HD_ * 2;
    short* w2b  = (short*)w; w += (size_t)128 * HD_ * 2;
    float* qemb = (float*)w; w += (size_t)B_ * HD_ * 4;
    float* r0   = (float*)w; w += (size_t)B_ * 128 * 4;
    int* offs   = (int*)w;   w += (size_t)B_ * N_ * 4;
    int* deg    = (int*)w;   w += (size_t)B_ * N_ * 4;
    int* csr    = (int*)w;   w += (size_t)B_ * E_ * 4;
    // zeroed accumulator region
    char* zbase = w;
    float* cs1  = (float*)w; w += (size_t)B_ * HD_ * 4;
    float* cq1  = (float*)w; w += (size_t)B_ * HD_ * 4;
    float* cs2  = (float*)w; w += (size_t)B_ * HD_ * 4;
    float* cq2  = (float*)w; w += (size_t)B_ * HD_ * 4;
    float* zsum = (float*)w; w += (size_t)B_ * 128 * 4;
    float* zsq  = (float*)w; w += (size_t)B_ * 128 * 4;
    size_t zero_bytes = (size_t)(w - zbase);

    hipMemsetAsync(zbase, 0, zero_bytes, stream);

    k_fc_init<<<B_ * N_ / 16, 256, 0, stream>>>(h, fciw, fcib, bufA);
    k_graph<<<B_, 512, 0, stream>>>(src, dst, deg, offs, csr);

    // gather/convert can run early (independent of GIN pipeline)
    k_gather<<<(B_ * G_ * 128) / 256, 256, 0, stream>>>(gPos, emb, embB);
    k_w2cvt<<<(128 * 1024 / 8) / 256, 256, 0, stream>>>(fc_w, w2b);

    dim3 agrid(HD_ / 256, N_ / 64, B_);
    k_agg<<<agrid, 256, 0, stream>>>((const float4*)bufA, (float4*)bufY, deg, offs, csr, cs1, cq1);
    k_norm<<<(B_ * N_ * HD_ / 4) / 256, 256, 0, stream>>>((const float4*)bufY, (float4*)bufA,
                                                          (const float4*)cs1, (const float4*)cq1,
                                                          (const float4*)bn1g, (const float4*)bn1b);
    k_agg<<<agrid, 256, 0, stream>>>((const float4*)bufA, (float4*)bufY, deg, offs, csr, cs2, cq2);
    k_norm<<<(B_ * N_ * HD_ / 4) / 256, 256, 0, stream>>>((const float4*)bufY, (float4*)bufA,
                                                          (const float4*)cs2, (const float4*)cq2,
                                                          (const float4*)bn2g, (const float4*)bn2b);

    k_qemb<<<dim3(HD_ / 4 / 64, B_), 256, 0, stream>>>((const float4*)bufA, (float4*)qemb);
    k_r0<<<B_ * 128, 64, 0, stream>>>(fc_w, fc_b, qemb, r0);

    k_gemm<<<dim3(G_ / 32, B_), 512, 0, stream>>>(embB, w2b, r0, z, zsum, zsq);
    k_final<<<(B_ * G_) / 4, 256, 0, stream>>>(z, zsum, zsq, bn3g, bn3b, fc2w, fc2b, out);
}

// Round 3
// 179.376 us; speedup vs baseline: 2.5793x; 1.8059x over previous
//
#include <hip/hip_runtime.h>
#include <hip/hip_bf16.h>

#define B_ 8
#define N_ 512
#define E_ 8192
#define G_ 1024
#define V_ 100000
#define HD_ 1024
#define FIN_ 20
#define EPS_ 1e-5f

typedef __attribute__((ext_vector_type(8))) short bf16x8;
typedef __attribute__((ext_vector_type(4))) float f32x4;

__device__ inline short f2bf(float f) {
    unsigned u = __builtin_bit_cast(unsigned, f);
    unsigned r = (u + 0x7fffu + ((u >> 16) & 1u)) >> 16;
    return (short)r;
}

__device__ inline float4 nr4(float4 v, float4 sc, float4 sh) {
    float4 o;
    o.x = fmaxf(v.x * sc.x + sh.x, 0.f);
    o.y = fmaxf(v.y * sc.y + sh.y, 0.f);
    o.z = fmaxf(v.z * sc.z + sh.z, 0.f);
    o.w = fmaxf(v.w * sc.w + sh.w, 0.f);
    return o;
}

// ---------- x0[bn][d] = h[bn][:] @ fc_init_w[d][:] + bias[d] ----------
__global__ __launch_bounds__(256) void k_fc_init(const float* __restrict__ h,
                                                 const float* __restrict__ w,
                                                 const float* __restrict__ bias,
                                                 float* __restrict__ x0) {
    int nb = blockIdx.x * 16;
    int tid = threadIdx.x;
    __shared__ float hs[16 * FIN_];
    if (tid < 16 * FIN_) hs[tid] = h[nb * FIN_ + tid];
    __syncthreads();
#pragma unroll
    for (int dq = 0; dq < 4; ++dq) {
        int d = dq * 256 + tid;
        const float4* wr = (const float4*)&w[d * FIN_];
        float4 w4[5];
#pragma unroll
        for (int i = 0; i < 5; ++i) w4[i] = wr[i];
        float bsv = bias[d];
#pragma unroll 4
        for (int n = 0; n < 16; ++n) {
            const float* hn = &hs[n * FIN_];
            float acc = bsv;
#pragma unroll
            for (int i = 0; i < 5; ++i) {
                acc += w4[i].x * hn[i * 4 + 0] + w4[i].y * hn[i * 4 + 1] +
                       w4[i].z * hn[i * 4 + 2] + w4[i].w * hn[i * 4 + 3];
            }
            x0[(size_t)(nb + n) * HD_ + d] = acc;
        }
    }
}

// ---------- fused CSR build (int4 edge loads) ----------
__global__ __launch_bounds__(512) void k_graph(const int* __restrict__ src,
                                               const int* __restrict__ dst,
                                               int* __restrict__ deg, int* __restrict__ offs,
                                               int* __restrict__ csr) {
    int b = blockIdx.x, t = threadIdx.x;
    __shared__ int sdeg[N_], s[N_], scur[N_];
    sdeg[t] = 0;
    __syncthreads();
    const int4* dst4 = (const int4*)(dst + b * E_);
    const int4* src4 = (const int4*)(src + b * E_);
#pragma unroll
    for (int e4 = t; e4 < E_ / 4; e4 += 512) {
        int4 d4 = dst4[e4];
        atomicAdd(&sdeg[d4.x], 1);
        atomicAdd(&sdeg[d4.y], 1);
        atomicAdd(&sdeg[d4.z], 1);
        atomicAdd(&sdeg[d4.w], 1);
    }
    __syncthreads();
    int d = sdeg[t];
    s[t] = d;
    __syncthreads();
    for (int off = 1; off < N_; off <<= 1) {
        int v = (t >= off) ? s[t - off] : 0;
        __syncthreads();
        s[t] += v;
        __syncthreads();
    }
    int excl = s[t] - d;
    deg[b * N_ + t] = d;
    offs[b * N_ + t] = excl;
    scur[t] = excl;
    __syncthreads();
#pragma unroll
    for (int e4 = t; e4 < E_ / 4; e4 += 512) {
        int4 dd = dst4[e4];
        int4 ss = src4[e4];
        int p;
        p = atomicAdd(&scur[dd.x], 1); csr[b * E_ + p] = ss.x;
        p = atomicAdd(&scur[dd.y], 1); csr[b * E_ + p] = ss.y;
        p = atomicAdd(&scur[dd.z], 1); csr[b * E_ + p] = ss.z;
        p = atomicAdd(&scur[dd.w], 1); csr[b * E_ + p] = ss.w;
    }
}

// ---------- GIN aggregate (+optional fused BN1+ReLU on inputs) + BN partial stats ----------
// grid (HD/256, N/16, B), block 256 (64 float4-cols x 4 waves, 4 nodes/thread)
template <bool NORM>
__global__ __launch_bounds__(256) void k_agg_t(const float4* __restrict__ xin,
                                               float4* __restrict__ y,
                                               const int* __restrict__ deg,
                                               const int* __restrict__ offs,
                                               const int* __restrict__ csr,
                                               const float4* __restrict__ pcs,
                                               const float4* __restrict__ pcq,
                                               const float4* __restrict__ pg,
                                               const float4* __restrict__ pb,
                                               float* __restrict__ csum,
                                               float* __restrict__ csumsq) {
    int b = blockIdx.z;
    int rowbase = blockIdx.y * 16;
    int tx = threadIdx.x & 63, ty = threadIdx.x >> 6;
    int c4 = blockIdx.x * 64 + tx;
    const float4* xb = xin + (size_t)b * N_ * (HD_ / 4);
    float4 sc, sh;
    if (NORM) {
        float4 cs = pcs[b * (HD_ / 4) + c4], cq = pcq[b * (HD_ / 4) + c4];
        float4 g4 = pg[c4], b4 = pb[c4];
        float mu, s;
        mu = cs.x * (1.f / N_); s = rsqrtf(cq.x * (1.f / N_) - mu * mu + EPS_) * g4.x;
        sc.x = s; sh.x = b4.x - mu * s;
        mu = cs.y * (1.f / N_); s = rsqrtf(cq.y * (1.f / N_) - mu * mu + EPS_) * g4.y;
        sc.y = s; sh.y = b4.y - mu * s;
        mu = cs.z * (1.f / N_); s = rsqrtf(cq.z * (1.f / N_) - mu * mu + EPS_) * g4.z;
        sc.z = s; sh.z = b4.z - mu * s;
        mu = cs.w * (1.f / N_); s = rsqrtf(cq.w * (1.f / N_) - mu * mu + EPS_) * g4.w;
        sc.w = s; sh.w = b4.w - mu * s;
    }
    float4 ps = {0.f, 0.f, 0.f, 0.f}, pq = {0.f, 0.f, 0.f, 0.f};
#pragma unroll
    for (int rr = 0; rr < 4; ++rr) {
        int node = rowbase + ty * 4 + rr;
        int dg = deg[b * N_ + node];
        float4 v = xb[(size_t)node * (HD_ / 4) + c4];
        if (NORM) v = nr4(v, sc, sh);
        if (dg > 0) {
            int st = offs[b * N_ + node];
            const int* cb = csr + b * E_ + st;
            float4 ns = {0.f, 0.f, 0.f, 0.f};
            int i = 0;
            for (; i + 4 <= dg; i += 4) {
                int s0 = cb[i], s1 = cb[i + 1], s2 = cb[i + 2], s3 = cb[i + 3];
                float4 a0 = xb[(size_t)s0 * (HD_ / 4) + c4];
                float4 a1 = xb[(size_t)s1 * (HD_ / 4) + c4];
                float4 a2 = xb[(size_t)s2 * (HD_ / 4) + c4];
                float4 a3 = xb[(size_t)s3 * (HD_ / 4) + c4];
                if (NORM) {
                    a0 = nr4(a0, sc, sh); a1 = nr4(a1, sc, sh);
                    a2 = nr4(a2, sc, sh); a3 = nr4(a3, sc, sh);
                }
                ns.x += (a0.x + a1.x) + (a2.x + a3.x);
                ns.y += (a0.y + a1.y) + (a2.y + a3.y);
                ns.z += (a0.z + a1.z) + (a2.z + a3.z);
                ns.w += (a0.w + a1.w) + (a2.w + a3.w);
            }
            for (; i < dg; ++i) {
                int s0 = cb[i];
                float4 a0 = xb[(size_t)s0 * (HD_ / 4) + c4];
                if (NORM) a0 = nr4(a0, sc, sh);
                ns.x += a0.x; ns.y += a0.y; ns.z += a0.z; ns.w += a0.w;
            }
            float inv = 1.f / (float)dg;
            v.x += ns.x * inv; v.y += ns.y * inv; v.z += ns.z * inv; v.w += ns.w * inv;
        }
        y[((size_t)b * N_ + node) * (HD_ / 4) + c4] = v;
        ps.x += v.x; ps.y += v.y; ps.z += v.z; ps.w += v.w;
        pq.x += v.x * v.x; pq.y += v.y * v.y; pq.z += v.z * v.z; pq.w += v.w * v.w;
    }
    __shared__ float4 red[256];
    red[threadIdx.x] = ps;
    __syncthreads();
    if (ty == 0) {
        float4 a = red[tx], b1 = red[64 + tx], c = red[128 + tx], d1 = red[192 + tx];
        atomicAdd(&csum[b * HD_ + c4 * 4 + 0], a.x + b1.x + c.x + d1.x);
        atomicAdd(&csum[b * HD_ + c4 * 4 + 1], a.y + b1.y + c.y + d1.y);
        atomicAdd(&csum[b * HD_ + c4 * 4 + 2], a.z + b1.z + c.z + d1.z);
        atomicAdd(&csum[b * HD_ + c4 * 4 + 3], a.w + b1.w + c.w + d1.w);
    }
    __syncthreads();
    red[threadIdx.x] = pq;
    __syncthreads();
    if (ty == 0) {
        float4 a = red[tx], b1 = red[64 + tx], c = red[128 + tx], d1 = red[192 + tx];
        atomicAdd(&csumsq[b * HD_ + c4 * 4 + 0], a.x + b1.x + c.x + d1.x);
        atomicAdd(&csumsq[b * HD_ + c4 * 4 + 1], a.y + b1.y + c.y + d1.y);
        atomicAdd(&csumsq[b * HD_ + c4 * 4 + 2], a.z + b1.z + c.z + d1.z);
        atomicAdd(&csumsq[b * HD_ + c4 * 4 + 3], a.w + b1.w + c.w + d1.w);
    }
}

// ---------- graph mean pool with fused BN2+ReLU ----------
// grid (HD/4/64, B), block 256
__global__ void k_qemb(const float4* __restrict__ x, const float4* __restrict__ pcs,
                       const float4* __restrict__ pcq, const float4* __restrict__ pg,
                       const float4* __restrict__ pb, float4* __restrict__ qemb) {
    int b = blockIdx.y;
    int tx = threadIdx.x & 63, ty = threadIdx.x >> 6;
    int d4 = blockIdx.x * 64 + tx;
    float4 cs = pcs[b * (HD_ / 4) + d4], cq = pcq[b * (HD_ / 4) + d4];
    float4 g4 = pg[d4], b4 = pb[d4];
    float4 sc, sh;
    float mu, s0;
    mu = cs.x * (1.f / N_); s0 = rsqrtf(cq.x * (1.f / N_) - mu * mu + EPS_) * g4.x;
    sc.x = s0; sh.x = b4.x - mu * s0;
    mu = cs.y * (1.f / N_); s0 = rsqrtf(cq.y * (1.f / N_) - mu * mu + EPS_) * g4.y;
    sc.y = s0; sh.y = b4.y - mu * s0;
    mu = cs.z * (1.f / N_); s0 = rsqrtf(cq.z * (1.f / N_) - mu * mu + EPS_) * g4.z;
    sc.z = s0; sh.z = b4.z - mu * s0;
    mu = cs.w * (1.f / N_); s0 = rsqrtf(cq.w * (1.f / N_) - mu * mu + EPS_) * g4.w;
    sc.w = s0; sh.w = b4.w - mu * s0;
    const float4* xb = x + (size_t)b * N_ * (HD_ / 4);
    float4 s = {0.f, 0.f, 0.f, 0.f};
    for (int n = ty; n < N_; n += 4) {
        float4 v = nr4(xb[(size_t)n * (HD_ / 4) + d4], sc, sh);
        s.x += v.x; s.y += v.y; s.z += v.z; s.w += v.w;
    }
    __shared__ float4 red[256];
    red[threadIdx.x] = s;
    __syncthreads();
    if (ty == 0) {
        float4 a = red[tx], b1 = red[64 + tx], c = red[128 + tx], d1 = red[192 + tx];
        float4 o;
        o.x = (a.x + b1.x + c.x + d1.x) * (1.f / N_);
        o.y = (a.y + b1.y + c.y + d1.y) * (1.f / N_);
        o.z = (a.z + b1.z + c.z + d1.z) * (1.f / N_);
        o.w = (a.w + b1.w + c.w + d1.w) * (1.f / N_);
        qemb[b * (HD_ / 4) + d4] = o;
    }
}

// ---------- r0[b][j] = fc_b[j] + fc_w[j][0:1024] . qemb[b] ----------
__global__ void k_r0(const float* __restrict__ fc_w, const float* __restrict__ fc_b,
                     const float* __restrict__ qemb, float* __restrict__ r0) {
    int b = blockIdx.x >> 7;
    int j = blockIdx.x & 127;
    int lane = threadIdx.x;
    const float* wr = fc_w + (size_t)j * (2 * HD_);
    const float* q = qemb + b * HD_;
    float acc = 0.f;
    for (int d = lane; d < HD_; d += 64) acc += wr[d] * q[d];
    for (int off = 32; off; off >>= 1) acc += __shfl_down(acc, off, 64);
    if (lane == 0) r0[b * 128 + j] = acc + fc_b[j];
}

// ---------- fc_w[:,1024:2048] -> bf16 [128][1024] ----------
__global__ void k_w2cvt(const float* __restrict__ fc_w, short* __restrict__ w2) {
    int gid = blockIdx.x * blockDim.x + threadIdx.x;
    int j = gid >> 7;
    int t = gid & 127;
    const float4* srcp = (const float4*)&fc_w[(size_t)j * (2 * HD_) + HD_ + t * 8];
    float4 a = srcp[0], b = srcp[1];
    bf16x8 o;
    o[0] = f2bf(a.x); o[1] = f2bf(a.y); o[2] = f2bf(a.z); o[3] = f2bf(a.w);
    o[4] = f2bf(b.x); o[5] = f2bf(b.y); o[6] = f2bf(b.z); o[7] = f2bf(b.w);
    *(bf16x8*)&w2[(size_t)j * HD_ + t * 8] = o;
}

// ---------- MFMA GEMM, LDS-resident B in K-quarters; A straight from emb (f32->bf16) ----------
// grid (G/32, B), 512 thr = 8 waves; block tile 32g x 128j; wave: 16g x 32j
__global__ __launch_bounds__(512) void k_gemm(const int* __restrict__ gPos,
                                              const float* __restrict__ emb,
                                              const short* __restrict__ w2,
                                              const float* __restrict__ r0,
                                              float* __restrict__ z,
                                              float* __restrict__ zsum,
                                              float* __restrict__ zsq) {
    int b = blockIdx.y;
    int gbase = blockIdx.x * 32;
    int tid = threadIdx.x;
    int wave = tid >> 6, lane = tid & 63;
    int gq = wave >> 2;  // 0..1 -> 16 g
    int jq = wave & 3;   // 0..3 -> 32 j
    __shared__ int gidx[32];
    __shared__ short Bs[8 * 4 * 128 * 8];  // [kt][ls][j][8] = 64 KB per K-quarter
    if (tid < 32) gidx[tid] = gPos[b * G_ + gbase + tid];
    f32x4 acc0 = {0.f, 0.f, 0.f, 0.f}, acc1 = {0.f, 0.f, 0.f, 0.f};

    int sj = tid >> 2, spart = tid & 3;  // staging: thread -> (j row, k-part of 64)
    int row16 = lane & 15, ksub = lane >> 4;
    const size_t arow = (size_t)gidx[0];  // dummy to keep gidx live before barrier (unused)
    (void)arow;

    for (int kq = 0; kq < 4; ++kq) {
        if (kq) __syncthreads();
        // stage 128j x 256k bf16 quarter
#pragma unroll
        for (int i = 0; i < 8; ++i) {
            int kl = spart * 64 + i * 8;
            int kt = kl >> 5, ls = (kl >> 3) & 3;
            bf16x8 v = *(const bf16x8*)&w2[(size_t)sj * HD_ + kq * 256 + kl];
            *(bf16x8*)&Bs[((kt * 4 + ls) * 128 + sj) * 8] = v;
        }
        __syncthreads();
#pragma unroll
        for (int kt = 0; kt < 8; ++kt) {
            int grow = gidx[gq * 16 + row16];
            const float4* ap =
                (const float4*)&emb[(size_t)grow * HD_ + kq * 256 + kt * 32 + ksub * 8];
            float4 af0 = ap[0], af1 = ap[1];
            bf16x8 a;
            a[0] = f2bf(af0.x); a[1] = f2bf(af0.y); a[2] = f2bf(af0.z); a[3] = f2bf(af0.w);
            a[4] = f2bf(af1.x); a[5] = f2bf(af1.y); a[6] = f2bf(af1.z); a[7] = f2bf(af1.w);
            bf16x8 b0 = *(const bf16x8*)&Bs[((kt * 4 + ksub) * 128 + jq * 32 + row16) * 8];
            bf16x8 b1 = *(const bf16x8*)&Bs[((kt * 4 + ksub) * 128 + jq * 32 + 16 + row16) * 8];
            acc0 = __builtin_amdgcn_mfma_f32_16x16x32_bf16(a, b0, acc0, 0, 0, 0);
            acc1 = __builtin_amdgcn_mfma_f32_16x16x32_bf16(a, b1, acc1, 0, 0, 0);
        }
    }

    int col0 = jq * 32 + row16;
    int col1 = col0 + 16;
    int rbase = gq * 16 + ksub * 4;
    const float* r0b = r0 + b * 128;
    float r0c0 = r0b[col0], r0c1 = r0b[col1];
    float s0 = 0.f, q0 = 0.f, s1 = 0.f, q1 = 0.f;
#pragma unroll
    for (int v = 0; v < 4; ++v) {
        int g = gbase + rbase + v;
        float z0 = acc0[v] + r0c0;
        float z1 = acc1[v] + r0c1;
        z[(size_t)(b * G_ + g) * 128 + col0] = z0;
        z[(size_t)(b * G_ + g) * 128 + col1] = z1;
        s0 += z0; q0 += z0 * z0; s1 += z1; q1 += z1 * z1;
    }
    s0 += __shfl_xor(s0, 16, 64); s0 += __shfl_xor(s0, 32, 64);
    q0 += __shfl_xor(q0, 16, 64); q0 += __shfl_xor(q0, 32, 64);
    s1 += __shfl_xor(s1, 16, 64); s1 += __shfl_xor(s1, 32, 64);
    q1 += __shfl_xor(q1, 16, 64); q1 += __shfl_xor(q1, 32, 64);
    if (lane < 16) {
        atomicAdd(&zsum[b * 128 + col0], s0);
        atomicAdd(&zsq[b * 128 + col0], q0);
        atomicAdd(&zsum[b * 128 + col1], s1);
        atomicAdd(&zsq[b * 128 + col1], q1);
    }
}

// ---------- BN3 + relu + fc2 + sigmoid ----------
__global__ void k_final(const float* __restrict__ z, const float* __restrict__ zsum,
                        const float* __restrict__ zsumsq, const float* __restrict__ g3,
                        const float* __restrict__ b3, const float* __restrict__ fc2w,
                        const float* __restrict__ fc2b, float* __restrict__ out) {
    int wid = (blockIdx.x * blockDim.x + threadIdx.x) >> 6;
    int lane = threadIdx.x & 63;
    if (wid >= B_ * G_) return;
    int b = wid / G_;
    const float* zr = z + (size_t)wid * 128;
    float acc = 0.f;
#pragma unroll
    for (int t = 0; t < 2; ++t) {
        int j = lane + t * 64;
        float mu = zsum[b * 128 + j] * (1.f / G_);
        float var = zsumsq[b * 128 + j] * (1.f / G_) - mu * mu;
        float v = (zr[j] - mu) * rsqrtf(var + EPS_) * g3[j] + b3[j];
        v = v > 0.f ? v : 0.f;
        acc += v * fc2w[j];
    }
    for (int off = 32; off; off >>= 1) acc += __shfl_down(acc, off, 64);
    if (lane == 0) out[wid] = 1.f / (1.f + expf(-(acc + fc2b[0])));
}

extern "C" void kernel_launch(void* const* d_in, const int* in_sizes, int n_in,
                              void* d_out, int out_size, void* d_ws, size_t ws_size,
                              hipStream_t stream) {
    const float* h    = (const float*)d_in[0];
    const int*   src  = (const int*)d_in[1];
    const int*   dst  = (const int*)d_in[2];
    const int*   gPos = (const int*)d_in[3];
    const float* emb  = (const float*)d_in[4];
    const float* fciw = (const float*)d_in[5];
    const float* fcib = (const float*)d_in[6];
    const float* bn1g = (const float*)d_in[7];
    const float* bn1b = (const float*)d_in[8];
    const float* bn2g = (const float*)d_in[9];
    const float* bn2b = (const float*)d_in[10];
    const float* fc_w = (const float*)d_in[11];
    const float* fc_b = (const float*)d_in[12];
    const float* bn3g = (const float*)d_in[13];
    const float* bn3b = (const float*)d_in[14];
    const float* fc2w = (const float*)d_in[15];
    const float* fc2b = (const float*)d_in[16];
    float* out = (float*)d_out;

    char* w = (char*)d_ws;
    float* bufA = (float*)w; w += (size_t)B_ * N_ * HD_ * 4;
    float* bufY = (float*)w; w += (size_t)B_ * N_ * HD_ * 4;
    float* z    = (float*)w; w += (size_t)B_ * G_ * 128 * 4;
    short* w2b  = (short*)w; w += (size_t)128 * HD_ * 2;
    float* qemb = (float*)w; w += (size_t)B_ * HD_ * 4;
    float* r0   = (float*)w; w += (size_t)B_ * 128 * 4;
    int* offs   = (int*)w;   w += (size_t)B_ * N_ * 4;
    int* deg    = (int*)w;   w += (size_t)B_ * N_ * 4;
    int* csr    = (int*)w;   w += (size_t)B_ * E_ * 4;
    // zeroed accumulator region
    char* zbase = w;
    float* cs1  = (float*)w; w += (size_t)B_ * HD_ * 4;
    float* cq1  = (float*)w; w += (size_t)B_ * HD_ * 4;
    float* cs2  = (float*)w; w += (size_t)B_ * HD_ * 4;
    float* cq2  = (float*)w; w += (size_t)B_ * HD_ * 4;
    float* zsum = (float*)w; w += (size_t)B_ * 128 * 4;
    float* zsq  = (float*)w; w += (size_t)B_ * 128 * 4;
    size_t zero_bytes = (size_t)(w - zbase);

    hipMemsetAsync(zbase, 0, zero_bytes, stream);

    k_w2cvt<<<(128 * 1024 / 8) / 256, 256, 0, stream>>>(fc_w, w2b);
    k_fc_init<<<B_ * N_ / 16, 256, 0, stream>>>(h, fciw, fcib, bufA);
    k_graph<<<B_, 512, 0, stream>>>(src, dst, deg, offs, csr);

    dim3 agrid(HD_ / 256, N_ / 16, B_);
    k_agg_t<false><<<agrid, 256, 0, stream>>>((const float4*)bufA, (float4*)bufY,
                                              deg, offs, csr,
                                              nullptr, nullptr, nullptr, nullptr,
                                              cs1, cq1);
    k_agg_t<true><<<agrid, 256, 0, stream>>>((const float4*)bufY, (float4*)bufA,
                                             deg, offs, csr,
                                             (const float4*)cs1, (const float4*)cq1,
                                             (const float4*)bn1g, (const float4*)bn1b,
                                             cs2, cq2);

    k_qemb<<<dim3(HD_ / 4 / 64, B_), 256, 0, stream>>>((const float4*)bufA,
                                                       (const float4*)cs2, (const float4*)cq2,
                                                       (const float4*)bn2g, (const float4*)bn2b,
                                                       (float4*)qemb);
    k_r0<<<B_ * 128, 64, 0, stream>>>(fc_w, fc_b, qemb, r0);

    k_gemm<<<dim3(G_ / 32, B_), 512, 0, stream>>>(gPos, emb, w2b, r0, z, zsum, zsq);
    k_final<<<(B_ * G_) / 4, 256, 0, stream>>>(z, zsum, zsq, bn3g, bn3b, fc2w, fc2b, out);
}

// Round 4
// 34.835 us; speedup vs baseline: 13.2813x; 5.1493x over previous
//
#include <hip/hip_runtime.h>
#include <hip/hip_bf16.h>

#define B_ 8
#define G_ 1024
#define HD_ 1024
#define EPS_ 1e-5f

// NOTE: The reference's BatchNorm over the G axis (training mode, batch stats)
// makes the output invariant to any per-(b,j) constant added to H @ fc_w.T.
// The broadcast-qemb half of H and fc_b are such constants -> the whole GIN
// pipeline (fc_init, graph agg, bn1/bn2, mean-pool, r0) cannot affect d_out.
// Only gPos, allDBGEmb, fc_w[:,1024:], bn3, fc2 matter.

typedef __attribute__((ext_vector_type(8))) short bf16x8;
typedef __attribute__((ext_vector_type(16))) float f32x16;

__device__ inline short bf1(float x) {
    return (short)__builtin_bit_cast(unsigned short, __float2bfloat16(x));
}
__device__ inline bf16x8 cvt8(float4 a, float4 b) {
    bf16x8 o;
    o[0] = bf1(a.x); o[1] = bf1(a.y); o[2] = bf1(a.z); o[3] = bf1(a.w);
    o[4] = bf1(b.x); o[5] = bf1(b.y); o[6] = bf1(b.z); o[7] = bf1(b.w);
    return o;
}

// LDS slab layouts: slab = 8-element k-chunk. Slab strides are (rows*8 + 2)
// shorts so consecutive slabs shift by 1 dword-bank -> ~2-way conflicts max.
#define ASLAB 258   // 32 rows * 8 shorts + 2 pad
#define BSLAB 1026  // 128 rows * 8 shorts + 2 pad

// ---------- z[b][g][j] = emb[gPos[b][g]] . fc_w[j][1024:2048]  (bf16 MFMA) ----------
// grid (32, 8): 32g x 128j tile per block; 4 waves, wave jq covers 32 j-cols,
// 32x32x16 MFMA over full K=1024 in 8 double-buffered 128-k phases.
__global__ __launch_bounds__(256) void k_gemm(const int* __restrict__ gPos,
                                              const float* __restrict__ emb,
                                              const float* __restrict__ fc_w,
                                              float* __restrict__ z,
                                              float* __restrict__ ps,
                                              float* __restrict__ pq) {
    int b = blockIdx.y, gblk = blockIdx.x;
    int gbase = gblk * 32;
    int tid = threadIdx.x;
    int jq = tid >> 6, lane = tid & 63;
    int l31 = lane & 31, kh = lane >> 5;

    __shared__ int gidx[32];
    __shared__ short As[2][16 * ASLAB];
    __shared__ short Bs[2][16 * BSLAB];

    if (tid < 32) gidx[tid] = gPos[b * G_ + gbase + tid];
    __syncthreads();

    int arow = tid >> 3, acp = tid & 7;   // A staging: 8 threads per emb row
    int brow = tid >> 1, bpar = tid & 1;  // B staging: 2 threads per fc_w row
    const float* abase = emb + (size_t)gidx[arow] * HD_;
    const float* bbase = fc_w + (size_t)brow * (2 * HD_) + HD_;

    f32x16 acc;
#pragma unroll
    for (int i = 0; i < 16; ++i) acc[i] = 0.f;

    // prologue: stage phase 0 into buffer 0
    {
        const float4* ap = (const float4*)(abase + acp * 8);
#pragma unroll
        for (int i = 0; i < 2; ++i)
            *(bf16x8*)&As[0][(acp + 8 * i) * ASLAB + arow * 8] =
                cvt8(ap[i * 16], ap[i * 16 + 1]);
        const float4* bp = (const float4*)(bbase + bpar * 8);
#pragma unroll
        for (int i = 0; i < 8; ++i)
            *(bf16x8*)&Bs[0][(bpar + 2 * i) * BSLAB + brow * 8] =
                cvt8(bp[i * 4], bp[i * 4 + 1]);
    }
    __syncthreads();

    for (int p = 0; p < 8; ++p) {
        int cur = p & 1;
        if (p < 7) {
            int nxt = cur ^ 1;
            const float4* ap = (const float4*)(abase + (p + 1) * 128 + acp * 8);
#pragma unroll
            for (int i = 0; i < 2; ++i)
                *(bf16x8*)&As[nxt][(acp + 8 * i) * ASLAB + arow * 8] =
                    cvt8(ap[i * 16], ap[i * 16 + 1]);
            const float4* bp = (const float4*)(bbase + (p + 1) * 128 + bpar * 8);
#pragma unroll
            for (int i = 0; i < 8; ++i)
                *(bf16x8*)&Bs[nxt][(bpar + 2 * i) * BSLAB + brow * 8] =
                    cvt8(bp[i * 4], bp[i * 4 + 1]);
        }
#pragma unroll
        for (int kt = 0; kt < 8; ++kt) {
            int c = kt * 2 + kh;
            bf16x8 a = *(const bf16x8*)&As[cur][c * ASLAB + l31 * 8];
            bf16x8 bv = *(const bf16x8*)&Bs[cur][c * BSLAB + (jq * 32 + l31) * 8];
            acc = __builtin_amdgcn_mfma_f32_32x32x16_bf16(a, bv, acc, 0, 0, 0);
        }
        __syncthreads();
    }

    // epilogue: z write + per-block BN partial sums (no atomics)
    int jcol = jq * 32 + l31;
    float s = 0.f, q = 0.f;
#pragma unroll
    for (int r = 0; r < 16; ++r) {
        int grow = (r & 3) + 8 * (r >> 2) + 4 * kh;  // verified 32x32 C/D layout
        float v = acc[r];
        z[(size_t)(b * G_ + gbase + grow) * 128 + jcol] = v;
        s += v;
        q += v * v;
    }
    s += __shfl_xor(s, 32, 64);
    q += __shfl_xor(q, 32, 64);
    if (lane < 32) {
        ps[(b * 32 + gblk) * 128 + jcol] = s;
        pq[(b * 32 + gblk) * 128 + jcol] = q;
    }
}

// ---------- BN3 stats: reduce 32 block-partials -> scale/shift per (b,j) ----------
__global__ void k_stats(const float* __restrict__ ps, const float* __restrict__ pq,
                        const float* __restrict__ g3, const float* __restrict__ b3,
                        float* __restrict__ scv, float* __restrict__ shv) {
    int b = blockIdx.x, j = threadIdx.x;
    float s = 0.f, q = 0.f;
#pragma unroll 8
    for (int t = 0; t < 32; ++t) {
        s += ps[(b * 32 + t) * 128 + j];
        q += pq[(b * 32 + t) * 128 + j];
    }
    float mu = s * (1.f / G_);
    float var = q * (1.f / G_) - mu * mu;
    float sc = g3[j] * rsqrtf(var + EPS_);
    scv[b * 128 + j] = sc;
    shv[b * 128 + j] = b3[j] - mu * sc;
}

// ---------- BN3 apply + relu + fc2 dot + sigmoid; one wave per (b,g) ----------
__global__ __launch_bounds__(256) void k_final(const float* __restrict__ z,
                                               const float* __restrict__ scv,
                                               const float* __restrict__ shv,
                                               const float* __restrict__ fc2w,
                                               const float* __restrict__ fc2b,
                                               float* __restrict__ out) {
    int wid = (blockIdx.x * blockDim.x + threadIdx.x) >> 6;
    int lane = threadIdx.x & 63;
    int b = wid >> 10;
    const float* zr = z + (size_t)wid * 128;
    float acc = 0.f;
#pragma unroll
    for (int t = 0; t < 2; ++t) {
        int j = lane + t * 64;
        float v = fmaf(zr[j], scv[b * 128 + j], shv[b * 128 + j]);
        v = fmaxf(v, 0.f);
        acc += v * fc2w[j];
    }
    for (int off = 32; off; off >>= 1) acc += __shfl_down(acc, off, 64);
    if (lane == 0) out[wid] = 1.f / (1.f + expf(-(acc + fc2b[0])));
}

extern "C" void kernel_launch(void* const* d_in, const int* in_sizes, int n_in,
                              void* d_out, int out_size, void* d_ws, size_t ws_size,
                              hipStream_t stream) {
    const int*   gPos = (const int*)d_in[3];
    const float* emb  = (const float*)d_in[4];
    const float* fc_w = (const float*)d_in[11];
    const float* bn3g = (const float*)d_in[13];
    const float* bn3b = (const float*)d_in[14];
    const float* fc2w = (const float*)d_in[15];
    const float* fc2b = (const float*)d_in[16];
    float* out = (float*)d_out;

    char* w = (char*)d_ws;
    float* z   = (float*)w; w += (size_t)B_ * G_ * 128 * 4;   // 4 MB
    float* ps  = (float*)w; w += (size_t)B_ * 32 * 128 * 4;   // 128 KB
    float* pq  = (float*)w; w += (size_t)B_ * 32 * 128 * 4;   // 128 KB
    float* scv = (float*)w; w += (size_t)B_ * 128 * 4;
    float* shv = (float*)w; w += (size_t)B_ * 128 * 4;

    k_gemm<<<dim3(32, B_), 256, 0, stream>>>(gPos, emb, fc_w, z, ps, pq);
    k_stats<<<B_, 128, 0, stream>>>(ps, pq, bn3g, bn3b, scv, shv);
    k_final<<<(B_ * G_) / 4, 256, 0, stream>>>(z, scv, shv, fc2w, fc2b, out);
}